// Round 2
// 751.289 us; speedup vs baseline: 1.2604x; 1.2604x over previous
//
#include <hip/hip_runtime.h>

typedef unsigned short u16;
typedef __attribute__((ext_vector_type(8))) short s8v;   // 8 bf16 (4 VGPRs) MFMA A/B frag
typedef __attribute__((ext_vector_type(4))) float f4v;   // MFMA C/D frag

#define MFMA16(a, b, c) __builtin_amdgcn_mfma_f32_16x16x32_bf16((a), (b), (c), 0, 0, 0)

// async global->LDS, 16B per lane; LDS dest = wave-uniform base + lane*16
#define GLOAD16(gp, lp) __builtin_amdgcn_global_load_lds(                      \
    (const __attribute__((address_space(1))) void*)(gp),                       \
    (__attribute__((address_space(3))) void*)(lp), 16, 0, 0)

__device__ inline float bf2f(u16 h) { return __uint_as_float(((unsigned)h) << 16); }
__device__ inline u16 f2bf(float f) {
    unsigned u = __float_as_uint(f);
    u += 0x7FFFu + ((u >> 16) & 1u);   // round-to-nearest-even
    return (u16)(u >> 16);
}

// ---------------------------------------------------------------------------
// Kernel 0: dtype probe. flag=1 -> inputs are fp32.
// ---------------------------------------------------------------------------
__global__ void probe_kernel(const u16* __restrict__ x16, int* __restrict__ flag) {
    int lane = threadIdx.x;
    int cnt = 0;
    for (int i = lane; i < 2048; i += 64) {
        float v = bf2f(x16[2 * i]);
        float a = fabsf(v);
        bool sane = (a == 0.0f) || (a > 1e-5f && a < 1e5f);  // NaN -> false
        if (!sane) cnt++;
    }
#pragma unroll
    for (int off = 32; off; off >>= 1) cnt += __shfl_xor(cnt, off);
    if (lane == 0) flag[0] = (cnt > 512) ? 1 : 0;
}

// ---------------------------------------------------------------------------
// Kernel 0b: weight transpose-convert. src [K][N] (fp32 or bf16) -> dst [N][K] bf16.
// 32x32 tiles via LDS. Gives GEMM a B^T operand so staging is linear k-contig.
// ---------------------------------------------------------------------------
__global__ __launch_bounds__(256) void transpose_convert_kernel(
    const void* __restrict__ src, u16* __restrict__ dst,
    const int* __restrict__ flagp, int K, int N) {
    __shared__ float t[32][33];
    int f = *flagp;
    int n0 = blockIdx.x * 32, k0 = blockIdx.y * 32;
    int tid = threadIdx.x;
    int r = tid >> 3, c4 = (tid & 7) * 4;
    if (f) {
        const float* s = (const float*)src + (size_t)(k0 + r) * N + n0 + c4;
        float4 v = *(const float4*)s;
        t[r][c4] = v.x; t[r][c4 + 1] = v.y; t[r][c4 + 2] = v.z; t[r][c4 + 3] = v.w;
    } else {
        const u16* s = (const u16*)src + (size_t)(k0 + r) * N + n0 + c4;
        uint2 v = *(const uint2*)s;
        t[r][c4]     = bf2f((u16)(v.x & 0xffff));
        t[r][c4 + 1] = bf2f((u16)(v.x >> 16));
        t[r][c4 + 2] = bf2f((u16)(v.y & 0xffff));
        t[r][c4 + 3] = bf2f((u16)(v.y >> 16));
    }
    __syncthreads();
    u16 o[4];
#pragma unroll
    for (int i = 0; i < 4; i++) o[i] = f2bf(t[c4 + i][r]);
    uint2 packed;
    packed.x = (unsigned)o[0] | ((unsigned)o[1] << 16);
    packed.y = (unsigned)o[2] | ((unsigned)o[3] << 16);
    *(uint2*)(dst + (size_t)(n0 + r) * K + k0 + c4) = packed;
}

// ---------------------------------------------------------------------------
// Kernel 1: LayerNorm (adaptive fp32/bf16 in, bf16 out), one block per row
// ---------------------------------------------------------------------------
__global__ __launch_bounds__(256) void ln_kernel(const void* __restrict__ xv,
                                                 const void* __restrict__ gv,
                                                 const void* __restrict__ bv,
                                                 u16* __restrict__ xn,
                                                 const int* __restrict__ flagp) {
    int f = *flagp;
    int row = blockIdx.x;
    int tid = threadIdx.x;
    int lane = tid & 63, wave = tid >> 6;

    float v[4];
    if (f) {
        const float* xr = (const float*)xv + (size_t)row * 1024;
        float4 a = ((const float4*)xr)[tid];
        v[0] = a.x; v[1] = a.y; v[2] = a.z; v[3] = a.w;
    } else {
        const u16* xr = (const u16*)xv + (size_t)row * 1024;
        uint2 raw = ((const uint2*)xr)[tid];
        v[0] = bf2f((u16)(raw.x & 0xffff));
        v[1] = bf2f((u16)(raw.x >> 16));
        v[2] = bf2f((u16)(raw.y & 0xffff));
        v[3] = bf2f((u16)(raw.y >> 16));
    }

    float s = v[0] + v[1] + v[2] + v[3];
    float ss = v[0]*v[0] + v[1]*v[1] + v[2]*v[2] + v[3]*v[3];
#pragma unroll
    for (int off = 32; off; off >>= 1) {
        s  += __shfl_xor(s, off);
        ss += __shfl_xor(ss, off);
    }
    __shared__ float red[8];
    if (lane == 0) { red[wave] = s; red[4 + wave] = ss; }
    __syncthreads();
    s  = red[0] + red[1] + red[2] + red[3];
    ss = red[4] + red[5] + red[6] + red[7];

    float mu  = s * (1.0f / 1024.0f);
    float var = ss * (1.0f / 1024.0f) - mu * mu;
    float rs  = rsqrtf(var + 1e-5f);

    u16 o[4];
#pragma unroll
    for (int i = 0; i < 4; i++) {
        int c = tid * 4 + i;
        float g = f ? ((const float*)gv)[c] : bf2f(((const u16*)gv)[c]);
        float b = f ? ((const float*)bv)[c] : bf2f(((const u16*)bv)[c]);
        float y = (v[i] - mu) * rs * g + b;
        o[i] = f2bf(y);
    }
    uint2 packed;
    packed.x = (unsigned)o[0] | ((unsigned)o[1] << 16);
    packed.y = (unsigned)o[2] | ((unsigned)o[3] << 16);
    ((uint2*)(xn + (size_t)row * 1024))[tid] = packed;
}

// ---------------------------------------------------------------------------
// Kernel 2/4: GEMM  C[M,N] = A[M,K] @ W^T[N,K]^T   (bf16 in, fp32 acc)
// m97 structure: BM=BN=128, BK=64, 256 threads = 4 waves (64x64 quadrant each),
// staging via global_load_lds width-16 into LINEAR LDS, 2-barrier K-loop.
// MODE 0: scatter epilogue -> q,k as [b,h,n,d], v as [b,h,d,n] (bf16, to ws)
// MODE 1: FP32 out: out[gm*N+gn] = acc + b_out[gn]
// ---------------------------------------------------------------------------
template <int MODE>
__global__ __launch_bounds__(256) void gemm_kernel(const u16* __restrict__ A,
                                                   const u16* __restrict__ WT,
                                                   const void* __restrict__ bias,
                                                   const int* __restrict__ flagp,
                                                   void* __restrict__ outv,
                                                   int M, int N, int K) {
    __shared__ __align__(16) u16 As[128 * 64];   // [m][k] linear, 16 KB
    __shared__ __align__(16) u16 Bs[128 * 64];   // [n][k] linear, 16 KB

    int tid = threadIdx.x;
    int lane = tid & 63, wave = tid >> 6;
    int quad = lane >> 4, l16 = lane & 15;
    int wr = wave >> 1, wc = wave & 1;
    int m0 = blockIdx.y * 128, n0 = blockIdx.x * 128;

    // staging geometry: per call-site a wave writes 1 KB = 8 rows x 64 k.
    // lane l covers row (l>>3), k ((l&7)*8); LDS dest = uniform base + l*16.
    int srow = lane >> 3;
    int sk   = (lane & 7) * 8;
    const u16* pa = A  + (size_t)(m0 + wave * 32 + srow) * K + sk;
    const u16* pb = WT + (size_t)(n0 + wave * 32 + srow) * K + sk;

    f4v acc[4][4];
#pragma unroll
    for (int i = 0; i < 4; i++)
#pragma unroll
        for (int j = 0; j < 4; j++) acc[i][j] = (f4v){0.f, 0.f, 0.f, 0.f};

    for (int k0 = 0; k0 < K; k0 += 64) {
        __syncthreads();          // previous iter's ds_reads done
#pragma unroll
        for (int cs = 0; cs < 4; cs++) {
            GLOAD16(pa + (size_t)cs * 8 * K + k0, &As[(wave * 32 + cs * 8) * 64]);
            GLOAD16(pb + (size_t)cs * 8 * K + k0, &Bs[(wave * 32 + cs * 8) * 64]);
        }
        __syncthreads();          // compiler drains vmcnt(0) before barrier

#pragma unroll
        for (int kc = 0; kc < 2; kc++) {
            s8v afr[4], bfr[4];
#pragma unroll
            for (int mi = 0; mi < 4; mi++)
                afr[mi] = *(const s8v*)&As[(wr * 64 + mi * 16 + l16) * 64 + kc * 32 + quad * 8];
#pragma unroll
            for (int ni = 0; ni < 4; ni++)
                bfr[ni] = *(const s8v*)&Bs[(wc * 64 + ni * 16 + l16) * 64 + kc * 32 + quad * 8];
#pragma unroll
            for (int mi = 0; mi < 4; mi++)
#pragma unroll
                for (int ni = 0; ni < 4; ni++)
                    acc[mi][ni] = MFMA16(afr[mi], bfr[ni], acc[mi][ni]);
        }
    }

    int f = (MODE == 1) ? *flagp : 0;

    // epilogue: C/D layout col=lane&15, row=quad*4+reg
#pragma unroll
    for (int mi = 0; mi < 4; mi++) {
#pragma unroll
        for (int ni = 0; ni < 4; ni++) {
#pragma unroll
            for (int r = 0; r < 4; r++) {
                int gm = m0 + wr * 64 + mi * 16 + quad * 4 + r;
                int gn = n0 + wc * 64 + ni * 16 + l16;
                float v = acc[mi][ni][r];
                if (MODE == 1) {
                    float bb = f ? ((const float*)bias)[gn]
                                 : bf2f(((const u16*)bias)[gn]);
                    ((float*)outv)[(size_t)gm * N + gn] = v + bb;
                } else {
                    u16* out = (u16*)outv;
                    int sel = gn >> 10, rem = gn & 1023;
                    int h = rem >> 6, d = rem & 63;
                    int b = gm >> 11, q = gm & 2047;
                    size_t dst;
                    if (sel == 2)  // v transposed: [b,h,d,n]
                        dst = ((size_t)(b * 16 + h) * 64 + d) * 2048 + q;
                    else           // q,k: [b,h,n,d]
                        dst = ((size_t)(b * 16 + h) * 2048 + q) * 64 + d;
                    out[(size_t)sel * 8388608 + dst] = f2bf(v);
                }
            }
        }
    }
}

// ---------------------------------------------------------------------------
// Kernel 3: flash attention. Block = 64 q-rows of one (b,h); 4 waves x 16 rows.
// K stored [b,h,n,d]; V stored transposed [b,h,d,n]; bias adaptive fp32/bf16.
// XCD-aware decode: d = ((g/8)*4 + b)*8 + (g%8), g = qt*16 + h.
//   -> all 4 batch-siblings of a (h,qt) bias slab share d%8 (same XCD L2),
//      and all qt-blocks of head h pin to XCD h%8 (K/V working set = 4 MB = L2).
// ---------------------------------------------------------------------------
__global__ __launch_bounds__(256) void attn_kernel(const u16* __restrict__ qg,
                                                   const u16* __restrict__ kg,
                                                   const u16* __restrict__ vtg,
                                                   const void* __restrict__ bias,
                                                   const int* __restrict__ flagp,
                                                   u16* __restrict__ out) {
    int d_ = blockIdx.x;
    int xcd = d_ & 7, t_ = d_ >> 3;
    int b = t_ & 3;
    int g = (t_ >> 2) * 8 + xcd;          // g = qt*16 + h
    int h = g & 15, qt = g >> 4;
    int q0 = qt * 64;
    int bh = b * 16 + h;
    int f = *flagp;

    int tid = threadIdx.x;
    int lane = tid & 63, wave = tid >> 6;
    int quad = lane >> 4, l16 = lane & 15;

    __shared__ __align__(16) u16 Ks[64][72];       // [kcol][kd]
    __shared__ __align__(16) u16 Vt[64][72];       // [d][kv]
    __shared__ __align__(16) u16 Ps[4][16][72];    // per-wave P round-trip

    // Q fragments: constant across K loop. A-layout: m = l16, k = quad*8+j
    const u16* qrow = qg + ((size_t)bh * 2048 + q0 + wave * 16 + l16) * 64;
    s8v qf0 = *(const s8v*)(qrow + quad * 8);
    s8v qf1 = *(const s8v*)(qrow + 32 + quad * 8);

    f4v oacc[4];
#pragma unroll
    for (int i = 0; i < 4; i++) oacc[i] = (f4v){0.f, 0.f, 0.f, 0.f};
    float mrow[4] = {-1e30f, -1e30f, -1e30f, -1e30f};
    float lrow[4] = {0.f, 0.f, 0.f, 0.f};

    const u16* kbase = kg + (size_t)bh * 2048 * 64;
    const u16* vbase = vtg + (size_t)bh * 64 * 2048;
    size_t boff = ((size_t)h * 2048 + q0 + wave * 16 + quad * 4) * 2048;
    const float* bbf = (const float*)bias + boff;
    const u16*   bbh = (const u16*)bias + boff;

    for (int kt = 0; kt < 2048; kt += 64) {
        __syncthreads();
        // stage K tile [64][64] and Vt tile [64][64]
#pragma unroll
        for (int c = tid; c < 512; c += 256) {
            int row = c >> 3, c8 = (c & 7) * 8;
            *(uint4*)&Ks[row][c8] = *(const uint4*)(kbase + (size_t)(kt + row) * 64 + c8);
            *(uint4*)&Vt[row][c8] = *(const uint4*)(vbase + (size_t)row * 2048 + kt + c8);
        }
        __syncthreads();

        // S = Q (16x64) @ K^T (64x64): 4 col-tiles, 2 k-chunks each
        f4v sc[4];
#pragma unroll
        for (int ni = 0; ni < 4; ni++) {
            s8v k0f = *(const s8v*)&Ks[ni * 16 + l16][quad * 8];
            s8v k1f = *(const s8v*)&Ks[ni * 16 + l16][32 + quad * 8];
            f4v t = (f4v){0.f, 0.f, 0.f, 0.f};
            t = MFMA16(qf0, k0f, t);
            t = MFMA16(qf1, k1f, t);
            sc[ni] = t;
        }

        // bias fetch (adaptive), then scale+bias in fp32.
        // C-layout: row=quad*4+r, col=ni*16+l16
        float barr[4][4];   // [ni][r]
        if (f) {
#pragma unroll
            for (int r = 0; r < 4; r++)
#pragma unroll
                for (int ni = 0; ni < 4; ni++)
                    barr[ni][r] = bbf[(size_t)r * 2048 + kt + ni * 16 + l16];
        } else {
#pragma unroll
            for (int r = 0; r < 4; r++)
#pragma unroll
                for (int ni = 0; ni < 4; ni++)
                    barr[ni][r] = bf2f(bbh[(size_t)r * 2048 + kt + ni * 16 + l16]);
        }
        float sv[4][4];   // [ni][r]
#pragma unroll
        for (int r = 0; r < 4; r++)
#pragma unroll
            for (int ni = 0; ni < 4; ni++)
                sv[ni][r] = sc[ni][r] * 0.125f + barr[ni][r];

        // online softmax over this 64-col slab, per q-row r (4 rows per quad)
        float mx[4];
#pragma unroll
        for (int r = 0; r < 4; r++) {
            mx[r] = fmaxf(fmaxf(sv[0][r], sv[1][r]), fmaxf(sv[2][r], sv[3][r]));
#pragma unroll
            for (int off = 1; off < 16; off <<= 1)
                mx[r] = fmaxf(mx[r], __shfl_xor(mx[r], off));
        }
        float alpha[4], rsum[4];
#pragma unroll
        for (int r = 0; r < 4; r++) {
            float mnew = fmaxf(mrow[r], mx[r]);
            alpha[r] = __expf(mrow[r] - mnew);
            mrow[r] = mnew;
            rsum[r] = 0.f;
#pragma unroll
            for (int ni = 0; ni < 4; ni++) {
                float p = __expf(sv[ni][r] - mnew);
                rsum[r] += p;
                Ps[wave][quad * 4 + r][ni * 16 + l16] = f2bf(p);
            }
        }
#pragma unroll
        for (int r = 0; r < 4; r++) {
#pragma unroll
            for (int off = 1; off < 16; off <<= 1)
                rsum[r] += __shfl_xor(rsum[r], off);
            lrow[r] = lrow[r] * alpha[r] + rsum[r];
        }
#pragma unroll
        for (int od = 0; od < 4; od++) {
            f4v t = oacc[od];
            t[0] *= alpha[0]; t[1] *= alpha[1]; t[2] *= alpha[2]; t[3] *= alpha[3];
            oacc[od] = t;
        }
        __syncthreads();   // P visible (and Ks/Vt reads done before next staging)

        // O += P (16x64) @ V (64x16-per-od). A=P from LDS, B=V^T rows.
        s8v pf0 = *(const s8v*)&Ps[wave][l16][quad * 8];
        s8v pf1 = *(const s8v*)&Ps[wave][l16][32 + quad * 8];
#pragma unroll
        for (int od = 0; od < 4; od++) {
            s8v vf0 = *(const s8v*)&Vt[od * 16 + l16][quad * 8];
            s8v vf1 = *(const s8v*)&Vt[od * 16 + l16][32 + quad * 8];
            oacc[od] = MFMA16(pf0, vf0, oacc[od]);
            oacc[od] = MFMA16(pf1, vf1, oacc[od]);
        }
    }

    // epilogue: normalize and write attn_out [b, q, h*64+d] bf16
    float inv[4];
#pragma unroll
    for (int r = 0; r < 4; r++) inv[r] = 1.0f / lrow[r];
#pragma unroll
    for (int od = 0; od < 4; od++) {
#pragma unroll
        for (int r = 0; r < 4; r++) {
            size_t dst = ((size_t)b * 2048 + q0 + wave * 16 + quad * 4 + r) * 1024 +
                         h * 64 + od * 16 + l16;
            out[dst] = f2bf(oacc[od][r] * inv[r]);
        }
    }
}

// ---------------------------------------------------------------------------
extern "C" void kernel_launch(void* const* d_in, const int* in_sizes, int n_in,
                              void* d_out, int out_size, void* d_ws, size_t ws_size,
                              hipStream_t stream) {
    const void* x      = d_in[0];
    const void* bias   = d_in[1];
    const void* w_qkv  = d_in[2];
    const void* w_out  = d_in[3];
    const void* b_out  = d_in[4];
    const void* gamma  = d_in[5];
    const void* beta   = d_in[6];

    u16* base = (u16*)d_ws;
    int* flag = (int*)d_ws;            // 128 B reserved
    u16* xn   = base + 64;             // 8192*1024 bf16            (16 MB)
    u16* qkv  = xn + 8388608;          // 3 * [b,h,n,d]/[b,h,d,n]   (48 MB)
    u16* attn = qkv + 3 * 8388608;     // 8192*1024 bf16            (16 MB)
    u16* wqT  = attn + 8388608;        // 3072x1024 bf16 (W_qkv^T)  (6 MB)
    u16* woT  = wqT + 3145728;         // 1024x1024 bf16 (W_out^T)  (2 MB)

    probe_kernel<<<dim3(1), dim3(64), 0, stream>>>((const u16*)x, flag);

    ln_kernel<<<dim3(8192), dim3(256), 0, stream>>>(x, gamma, beta, xn, flag);

    // W^T for the GEMMs: [K][N] -> [N][K] bf16
    transpose_convert_kernel<<<dim3(96, 32), dim3(256), 0, stream>>>(
        w_qkv, wqT, flag, 1024, 3072);
    transpose_convert_kernel<<<dim3(32, 32), dim3(256), 0, stream>>>(
        w_out, woT, flag, 1024, 1024);

    gemm_kernel<0><<<dim3(3072 / 128, 8192 / 128), dim3(256), 0, stream>>>(
        xn, wqT, nullptr, flag, qkv, 8192, 3072, 1024);

    attn_kernel<<<dim3(2048), dim3(256), 0, stream>>>(
        qkv, qkv + 8388608, qkv + 2 * 8388608, bias, flag, attn);

    gemm_kernel<1><<<dim3(1024 / 128, 8192 / 128), dim3(256), 0, stream>>>(
        attn, woT, b_out, flag, d_out, 8192, 1024, 1024);
}

// Round 3
// 719.833 us; speedup vs baseline: 1.3155x; 1.0437x over previous
//
#include <hip/hip_runtime.h>

typedef unsigned short u16;
typedef __attribute__((ext_vector_type(8))) short s8v;   // 8 bf16 (4 VGPRs) MFMA A/B frag
typedef __attribute__((ext_vector_type(4))) float f4v;   // MFMA C/D frag

#define MFMA16(a, b, c) __builtin_amdgcn_mfma_f32_16x16x32_bf16((a), (b), (c), 0, 0, 0)

// async global->LDS, 16B per lane; LDS dest = wave-uniform base + lane*16
#define GLOAD16(gp, lp) __builtin_amdgcn_global_load_lds(                      \
    (const __attribute__((address_space(1))) void*)(gp),                       \
    (__attribute__((address_space(3))) void*)(lp), 16, 0, 0)

__device__ inline float bf2f(u16 h) { return __uint_as_float(((unsigned)h) << 16); }
__device__ inline u16 f2bf(float f) {
    unsigned u = __float_as_uint(f);
    u += 0x7FFFu + ((u >> 16) & 1u);   // round-to-nearest-even
    return (u16)(u >> 16);
}

// ---------------------------------------------------------------------------
// Kernel 0: dtype probe. flag=1 -> inputs are fp32.
// ---------------------------------------------------------------------------
__global__ void probe_kernel(const u16* __restrict__ x16, int* __restrict__ flag) {
    int lane = threadIdx.x;
    int cnt = 0;
    for (int i = lane; i < 2048; i += 64) {
        float v = bf2f(x16[2 * i]);
        float a = fabsf(v);
        bool sane = (a == 0.0f) || (a > 1e-5f && a < 1e5f);  // NaN -> false
        if (!sane) cnt++;
    }
#pragma unroll
    for (int off = 32; off; off >>= 1) cnt += __shfl_xor(cnt, off);
    if (lane == 0) flag[0] = (cnt > 512) ? 1 : 0;
}

// ---------------------------------------------------------------------------
// Kernel 0b: weight transpose-convert. src [K][N] (fp32 or bf16) -> dst [N][K] bf16.
// ---------------------------------------------------------------------------
__global__ __launch_bounds__(256) void transpose_convert_kernel(
    const void* __restrict__ src, u16* __restrict__ dst,
    const int* __restrict__ flagp, int K, int N) {
    __shared__ float t[32][33];
    int f = *flagp;
    int n0 = blockIdx.x * 32, k0 = blockIdx.y * 32;
    int tid = threadIdx.x;
    int r = tid >> 3, c4 = (tid & 7) * 4;
    if (f) {
        const float* s = (const float*)src + (size_t)(k0 + r) * N + n0 + c4;
        float4 v = *(const float4*)s;
        t[r][c4] = v.x; t[r][c4 + 1] = v.y; t[r][c4 + 2] = v.z; t[r][c4 + 3] = v.w;
    } else {
        const u16* s = (const u16*)src + (size_t)(k0 + r) * N + n0 + c4;
        uint2 v = *(const uint2*)s;
        t[r][c4]     = bf2f((u16)(v.x & 0xffff));
        t[r][c4 + 1] = bf2f((u16)(v.x >> 16));
        t[r][c4 + 2] = bf2f((u16)(v.y & 0xffff));
        t[r][c4 + 3] = bf2f((u16)(v.y >> 16));
    }
    __syncthreads();
    u16 o[4];
#pragma unroll
    for (int i = 0; i < 4; i++) o[i] = f2bf(t[c4 + i][r]);
    uint2 packed;
    packed.x = (unsigned)o[0] | ((unsigned)o[1] << 16);
    packed.y = (unsigned)o[2] | ((unsigned)o[3] << 16);
    *(uint2*)(dst + (size_t)(n0 + r) * K + k0 + c4) = packed;
}

// ---------------------------------------------------------------------------
// Kernel 0c: V transpose  [bh][n][64] -> [bh][64][n]  (bf16, coalesced both sides)
// ---------------------------------------------------------------------------
__global__ __launch_bounds__(256) void transpose_v_kernel(const u16* __restrict__ v,
                                                          u16* __restrict__ vt) {
    __shared__ u16 t[64][72];
    int bh = blockIdx.y;
    int n0 = blockIdx.x * 64;
    int tid = threadIdx.x;
    int r = tid >> 2, c = (tid & 3) * 16;
    const u16* src = v + ((size_t)bh * 2048 + n0 + r) * 64 + c;
    *(uint4*)&t[r][c]     = *(const uint4*)src;
    *(uint4*)&t[r][c + 8] = *(const uint4*)(src + 8);
    __syncthreads();
    u16 o[16];
#pragma unroll
    for (int i = 0; i < 16; i++) o[i] = t[c + i][r];
    u16* dst = vt + ((size_t)bh * 64 + r) * 2048 + n0 + c;
    *(uint4*)dst       = *(const uint4*)&o[0];
    *(uint4*)(dst + 8) = *(const uint4*)&o[8];
}

// ---------------------------------------------------------------------------
// Kernel 1: LayerNorm (adaptive fp32/bf16 in, bf16 out), one block per row
// ---------------------------------------------------------------------------
__global__ __launch_bounds__(256) void ln_kernel(const void* __restrict__ xv,
                                                 const void* __restrict__ gv,
                                                 const void* __restrict__ bv,
                                                 u16* __restrict__ xn,
                                                 const int* __restrict__ flagp) {
    int f = *flagp;
    int row = blockIdx.x;
    int tid = threadIdx.x;
    int lane = tid & 63, wave = tid >> 6;

    float v[4];
    if (f) {
        const float* xr = (const float*)xv + (size_t)row * 1024;
        float4 a = ((const float4*)xr)[tid];
        v[0] = a.x; v[1] = a.y; v[2] = a.z; v[3] = a.w;
    } else {
        const u16* xr = (const u16*)xv + (size_t)row * 1024;
        uint2 raw = ((const uint2*)xr)[tid];
        v[0] = bf2f((u16)(raw.x & 0xffff));
        v[1] = bf2f((u16)(raw.x >> 16));
        v[2] = bf2f((u16)(raw.y & 0xffff));
        v[3] = bf2f((u16)(raw.y >> 16));
    }

    float s = v[0] + v[1] + v[2] + v[3];
    float ss = v[0]*v[0] + v[1]*v[1] + v[2]*v[2] + v[3]*v[3];
#pragma unroll
    for (int off = 32; off; off >>= 1) {
        s  += __shfl_xor(s, off);
        ss += __shfl_xor(ss, off);
    }
    __shared__ float red[8];
    if (lane == 0) { red[wave] = s; red[4 + wave] = ss; }
    __syncthreads();
    s  = red[0] + red[1] + red[2] + red[3];
    ss = red[4] + red[5] + red[6] + red[7];

    float mu  = s * (1.0f / 1024.0f);
    float var = ss * (1.0f / 1024.0f) - mu * mu;
    float rs  = rsqrtf(var + 1e-5f);

    u16 o[4];
#pragma unroll
    for (int i = 0; i < 4; i++) {
        int c = tid * 4 + i;
        float g = f ? ((const float*)gv)[c] : bf2f(((const u16*)gv)[c]);
        float b = f ? ((const float*)bv)[c] : bf2f(((const u16*)bv)[c]);
        float y = (v[i] - mu) * rs * g + b;
        o[i] = f2bf(y);
    }
    uint2 packed;
    packed.x = (unsigned)o[0] | ((unsigned)o[1] << 16);
    packed.y = (unsigned)o[2] | ((unsigned)o[3] << 16);
    ((uint2*)(xn + (size_t)row * 1024))[tid] = packed;
}

// ---------------------------------------------------------------------------
// Kernel 2/4: GEMM  C[M,N] = A[M,K] @ W^T[N,K]^T   (bf16 in, fp32 acc)
// m97 structure: BM=BN=128, BK=64, 256 threads = 4 waves, global_load_lds staging.
// MODE 0: epilogue -> q,k,v ALL as [b,h,n,d] bf16 (coalesced; V transposed later)
// MODE 1: FP32 out: out[gm*N+gn] = acc + b_out[gn]
// ---------------------------------------------------------------------------
template <int MODE>
__global__ __launch_bounds__(256) void gemm_kernel(const u16* __restrict__ A,
                                                   const u16* __restrict__ WT,
                                                   const void* __restrict__ bias,
                                                   const int* __restrict__ flagp,
                                                   void* __restrict__ outv,
                                                   int M, int N, int K) {
    __shared__ __align__(16) u16 As[128 * 64];   // [m][k] linear, 16 KB
    __shared__ __align__(16) u16 Bs[128 * 64];   // [n][k] linear, 16 KB

    int tid = threadIdx.x;
    int lane = tid & 63, wave = tid >> 6;
    int quad = lane >> 4, l16 = lane & 15;
    int wr = wave >> 1, wc = wave & 1;
    int m0 = blockIdx.y * 128, n0 = blockIdx.x * 128;

    int srow = lane >> 3;
    int sk   = (lane & 7) * 8;
    const u16* pa = A  + (size_t)(m0 + wave * 32 + srow) * K + sk;
    const u16* pb = WT + (size_t)(n0 + wave * 32 + srow) * K + sk;

    f4v acc[4][4];
#pragma unroll
    for (int i = 0; i < 4; i++)
#pragma unroll
        for (int j = 0; j < 4; j++) acc[i][j] = (f4v){0.f, 0.f, 0.f, 0.f};

    for (int k0 = 0; k0 < K; k0 += 64) {
        __syncthreads();
#pragma unroll
        for (int cs = 0; cs < 4; cs++) {
            GLOAD16(pa + (size_t)cs * 8 * K + k0, &As[(wave * 32 + cs * 8) * 64]);
            GLOAD16(pb + (size_t)cs * 8 * K + k0, &Bs[(wave * 32 + cs * 8) * 64]);
        }
        __syncthreads();

#pragma unroll
        for (int kc = 0; kc < 2; kc++) {
            s8v afr[4], bfr[4];
#pragma unroll
            for (int mi = 0; mi < 4; mi++)
                afr[mi] = *(const s8v*)&As[(wr * 64 + mi * 16 + l16) * 64 + kc * 32 + quad * 8];
#pragma unroll
            for (int ni = 0; ni < 4; ni++)
                bfr[ni] = *(const s8v*)&Bs[(wc * 64 + ni * 16 + l16) * 64 + kc * 32 + quad * 8];
#pragma unroll
            for (int mi = 0; mi < 4; mi++)
#pragma unroll
                for (int ni = 0; ni < 4; ni++)
                    acc[mi][ni] = MFMA16(afr[mi], bfr[ni], acc[mi][ni]);
        }
    }

    int f = (MODE == 1) ? *flagp : 0;

    // epilogue: C/D layout col=lane&15, row=quad*4+reg
#pragma unroll
    for (int mi = 0; mi < 4; mi++) {
#pragma unroll
        for (int ni = 0; ni < 4; ni++) {
#pragma unroll
            for (int r = 0; r < 4; r++) {
                int gm = m0 + wr * 64 + mi * 16 + quad * 4 + r;
                int gn = n0 + wc * 64 + ni * 16 + l16;
                float v = acc[mi][ni][r];
                if (MODE == 1) {
                    float bb = f ? ((const float*)bias)[gn]
                                 : bf2f(((const u16*)bias)[gn]);
                    ((float*)outv)[(size_t)gm * N + gn] = v + bb;
                } else {
                    u16* out = (u16*)outv;
                    int sel = gn >> 10, rem = gn & 1023;
                    int h = rem >> 6, d = rem & 63;
                    int b = gm >> 11, q = gm & 2047;
                    // q,k,v all [b,h,n,d] (coalesced 32B segments per 16 lanes)
                    size_t dst = ((size_t)(b * 16 + h) * 2048 + q) * 64 + d;
                    out[(size_t)sel * 8388608 + dst] = f2bf(v);
                }
            }
        }
    }
}

// ---------------------------------------------------------------------------
// Kernel 3: flash attention. Block = 64 q-rows of one (b,h); 4 waves x 16 rows.
// K [b,h,n,d]; V transposed [b,h,d,n]; bias adaptive fp32/bf16.
// XCD-aware decode (unchanged). Staging via global_load_lds into LINEAR LDS with
// XOR swizzle (rule 21): pre-swizzled global SOURCE col ((l&7)^(l>>3))*16, and
// read-side col XOR ((row&7)<<4). Two barriers/iter (P round-trip is wave-private).
// ---------------------------------------------------------------------------
__global__ __launch_bounds__(256) void attn_kernel(const u16* __restrict__ qg,
                                                   const u16* __restrict__ kg,
                                                   const u16* __restrict__ vtg,
                                                   const void* __restrict__ bias,
                                                   const int* __restrict__ flagp,
                                                   u16* __restrict__ out) {
    int d_ = blockIdx.x;
    int xcd = d_ & 7, t_ = d_ >> 3;
    int b = t_ & 3;
    int g = (t_ >> 2) * 8 + xcd;          // g = qt*16 + h
    int h = g & 15, qt = g >> 4;
    int q0 = qt * 64;
    int bh = b * 16 + h;
    int f = *flagp;

    int tid = threadIdx.x;
    int lane = tid & 63, wave = tid >> 6;
    int quad = lane >> 4, l16 = lane & 15;

    __shared__ __align__(16) u16 Ks[64 * 64];      // linear [kv][d], swizzled
    __shared__ __align__(16) u16 Vt[64 * 64];      // linear [d][kv], swizzled
    __shared__ __align__(16) u16 Ps[4][16][72];    // per-wave P round-trip

    // Q fragments: constant across K loop. A-layout: m = l16, k = quad*8+j
    const u16* qrow = qg + ((size_t)bh * 2048 + q0 + wave * 16 + l16) * 64;
    s8v qf0 = *(const s8v*)(qrow + quad * 8);
    s8v qf1 = *(const s8v*)(qrow + 32 + quad * 8);

    f4v oacc[4];
#pragma unroll
    for (int i = 0; i < 4; i++) oacc[i] = (f4v){0.f, 0.f, 0.f, 0.f};
    float mrow[4] = {-1e30f, -1e30f, -1e30f, -1e30f};
    float lrow[4] = {0.f, 0.f, 0.f, 0.f};

    const u16* kbase = kg + (size_t)bh * 2048 * 64;
    const u16* vbase = vtg + (size_t)bh * 64 * 2048;

    // staging: per wave 2 chunks of 8 rows each for K and Vt.
    // lane l: row chunk-offset l>>3, swizzled source col ((l&7)^(l>>3))*16 bytes.
    int srow = lane >> 3;
    int scol = ((lane & 7) ^ srow) * 16;
    const char* kp = (const char*)kbase + ((size_t)(wave * 16 + srow)) * 128 + scol;
    const char* vp = (const char*)vbase + ((size_t)(wave * 16 + srow)) * 4096 + scol;
    u16* ksl = &Ks[wave * 16 * 64];      // wave-uniform LDS bases (1 KB per GLOAD)
    u16* vsl = &Vt[wave * 16 * 64];

    int xr = (l16 & 7) << 4;             // read-side XOR (row&7 == l16&7 for all reads)

    size_t boff = ((size_t)h * 2048 + q0 + wave * 16 + quad * 4) * 2048;
    const float* bbf = (const float*)bias + boff;
    const u16*   bbh = (const u16*)bias + boff;

    for (int kt = 0; kt < 2048; kt += 64) {
        __syncthreads();                 // prior iter's Ks/Vt reads done
        GLOAD16(kp, ksl);
        GLOAD16(kp + 1024, ksl + 512);           // +8 K rows (8*128B)
        GLOAD16(vp, vsl);
        GLOAD16(vp + 8 * 4096, vsl + 512);       // +8 V rows
        kp += 64 * 128;                  // next K tile: +64 rows
        vp += 128;                       // next Vt tile: +64 kv cols
        __syncthreads();                 // vmcnt(0) drained before barrier

        // S = Q (16x64) @ K^T: rows ni*16+l16 of Ks, swizzled cols
        f4v sc[4];
#pragma unroll
        for (int ni = 0; ni < 4; ni++) {
            const char* krow = (const char*)Ks + (ni * 16 + l16) * 128;
            s8v k0f = *(const s8v*)(krow + ((quad * 16) ^ xr));
            s8v k1f = *(const s8v*)(krow + ((64 + quad * 16) ^ xr));
            f4v t = (f4v){0.f, 0.f, 0.f, 0.f};
            t = MFMA16(qf0, k0f, t);
            t = MFMA16(qf1, k1f, t);
            sc[ni] = t;
        }

        // bias fetch (adaptive), then scale+bias in fp32.
        float barr[4][4];   // [ni][r]
        if (f) {
#pragma unroll
            for (int r = 0; r < 4; r++)
#pragma unroll
                for (int ni = 0; ni < 4; ni++)
                    barr[ni][r] = bbf[(size_t)r * 2048 + kt + ni * 16 + l16];
        } else {
#pragma unroll
            for (int r = 0; r < 4; r++)
#pragma unroll
                for (int ni = 0; ni < 4; ni++)
                    barr[ni][r] = bf2f(bbh[(size_t)r * 2048 + kt + ni * 16 + l16]);
        }
        float sv[4][4];   // [ni][r]
#pragma unroll
        for (int r = 0; r < 4; r++)
#pragma unroll
            for (int ni = 0; ni < 4; ni++)
                sv[ni][r] = sc[ni][r] * 0.125f + barr[ni][r];

        // online softmax over this 64-col slab
        float mx[4];
#pragma unroll
        for (int r = 0; r < 4; r++) {
            mx[r] = fmaxf(fmaxf(sv[0][r], sv[1][r]), fmaxf(sv[2][r], sv[3][r]));
#pragma unroll
            for (int off = 1; off < 16; off <<= 1)
                mx[r] = fmaxf(mx[r], __shfl_xor(mx[r], off));
        }
        float alpha[4], rsum[4];
#pragma unroll
        for (int r = 0; r < 4; r++) {
            float mnew = fmaxf(mrow[r], mx[r]);
            alpha[r] = __expf(mrow[r] - mnew);
            mrow[r] = mnew;
            rsum[r] = 0.f;
#pragma unroll
            for (int ni = 0; ni < 4; ni++) {
                float p = __expf(sv[ni][r] - mnew);
                rsum[r] += p;
                Ps[wave][quad * 4 + r][ni * 16 + l16] = f2bf(p);
            }
        }
#pragma unroll
        for (int r = 0; r < 4; r++) {
#pragma unroll
            for (int off = 1; off < 16; off <<= 1)
                rsum[r] += __shfl_xor(rsum[r], off);
            lrow[r] = lrow[r] * alpha[r] + rsum[r];
        }
#pragma unroll
        for (int od = 0; od < 4; od++) {
            f4v t = oacc[od];
            t[0] *= alpha[0]; t[1] *= alpha[1]; t[2] *= alpha[2]; t[3] *= alpha[3];
            oacc[od] = t;
        }
        // NO barrier: Ps round-trip is wave-private (DS ops in-order per wave)

        // O += P (16x64) @ V. A=P from LDS, B=V^T rows (swizzled cols).
        s8v pf0 = *(const s8v*)&Ps[wave][l16][quad * 8];
        s8v pf1 = *(const s8v*)&Ps[wave][l16][32 + quad * 8];
#pragma unroll
        for (int od = 0; od < 4; od++) {
            const char* vrow = (const char*)Vt + (od * 16 + l16) * 128;
            s8v vf0 = *(const s8v*)(vrow + ((quad * 16) ^ xr));
            s8v vf1 = *(const s8v*)(vrow + ((64 + quad * 16) ^ xr));
            oacc[od] = MFMA16(pf0, vf0, oacc[od]);
            oacc[od] = MFMA16(pf1, vf1, oacc[od]);
        }
    }

    // epilogue: normalize and write attn_out [b, q, h*64+d] bf16
    float inv[4];
#pragma unroll
    for (int r = 0; r < 4; r++) inv[r] = 1.0f / lrow[r];
#pragma unroll
    for (int od = 0; od < 4; od++) {
#pragma unroll
        for (int r = 0; r < 4; r++) {
            size_t dst = ((size_t)b * 2048 + q0 + wave * 16 + quad * 4 + r) * 1024 +
                         h * 64 + od * 16 + l16;
            out[dst] = f2bf(oacc[od][r] * inv[r]);
        }
    }
}

// ---------------------------------------------------------------------------
extern "C" void kernel_launch(void* const* d_in, const int* in_sizes, int n_in,
                              void* d_out, int out_size, void* d_ws, size_t ws_size,
                              hipStream_t stream) {
    const void* x      = d_in[0];
    const void* bias   = d_in[1];
    const void* w_qkv  = d_in[2];
    const void* w_out  = d_in[3];
    const void* b_out  = d_in[4];
    const void* gamma  = d_in[5];
    const void* beta   = d_in[6];

    u16* base = (u16*)d_ws;
    int* flag = (int*)d_ws;            // 128 B reserved
    u16* xn   = base + 64;             // 8192*1024 bf16 (16 MB) -> reused as Vt
    u16* qkv  = xn + 8388608;          // 3 * [b,h,n,d]             (48 MB)
    u16* attn = qkv + 3 * 8388608;     // 8192*1024 bf16            (16 MB)
    u16* wqT  = attn + 8388608;        // 3072x1024 bf16 (W_qkv^T)  (6 MB)
    u16* woT  = wqT + 3145728;         // 1024x1024 bf16 (W_out^T)  (2 MB)

    probe_kernel<<<dim3(1), dim3(64), 0, stream>>>((const u16*)x, flag);

    ln_kernel<<<dim3(8192), dim3(256), 0, stream>>>(x, gamma, beta, xn, flag);

    transpose_convert_kernel<<<dim3(96, 32), dim3(256), 0, stream>>>(
        w_qkv, wqT, flag, 1024, 3072);
    transpose_convert_kernel<<<dim3(32, 32), dim3(256), 0, stream>>>(
        w_out, woT, flag, 1024, 1024);

    gemm_kernel<0><<<dim3(3072 / 128, 8192 / 128), dim3(256), 0, stream>>>(
        xn, wqT, nullptr, flag, qkv, 8192, 3072, 1024);

    // V [b,h,n,d] -> Vt [b,h,d,n]; xn is dead after gemm0, reuse it
    transpose_v_kernel<<<dim3(32, 64), dim3(256), 0, stream>>>(
        qkv + 2 * 8388608, xn);

    attn_kernel<<<dim3(2048), dim3(256), 0, stream>>>(
        qkv, qkv + 8388608, xn, bias, flag, attn);

    gemm_kernel<1><<<dim3(1024 / 128, 8192 / 128), dim3(256), 0, stream>>>(
        attn, woT, b_out, flag, d_out, 8192, 1024, 1024);
}